// Round 5
// baseline (2222.060 us; speedup 1.0000x reference)
//
#include <hip/hip_runtime.h>

// 4-layer LSTM (B=1024,T=512,H=64,G=256) + FC head.
// Kernel A (lstm_split): 128 blocks x 512 threads. Block = (role, 16-row chunk):
//   role 0 = layers 0+1 (producer), role 1 = layers 2+3 + FC head (consumer).
//   Within a block: wave-group (4 waves) = layer, skew 1 superstep, LDS tile handoff.
//   ONE cross-block boundary (h1 -> L2) via ring in d_ws: R slots (8-16), skew D=6,
//   overlapped acquire polls, per-step prefetch; producer/consumer never spin in steady state.
// Kernel B (lstm_fused): round-4 all-in-one fallback when ws_size is too small for R>=8.
// Measured basis: cell is transcendental-issue-bound (~16 cyc per v_exp/v_rcp wave64);
// splitting 2+2 doubles active SIMDs -> halves the per-SIMD trans load.

#define TLEN 512
#define NCH  64
#define AG   __HIP_MEMORY_SCOPE_AGENT
#define SPIN_CAP 500000

typedef __bf16 bf16x8 __attribute__((ext_vector_type(8)));
typedef float  f32x4  __attribute__((ext_vector_type(4)));

struct Params {
  const float* x;
  const float* wih[4]; const float* whh[4];
  const float* bih[4]; const float* bhh[4];
  const float* fc1w; const float* fc1b;
  const float* fc2w; const float* fc2b;
  float* out; char* ws;
  int R; int Rmask; int D;
};

__device__ __forceinline__ bf16x8 bfzero() {
  union { unsigned long long u[2]; bf16x8 v; } z; z.u[0] = 0ull; z.u[1] = 0ull; return z.v;
}
__device__ __forceinline__ float fast_sigmoid(float x) {
  return __builtin_amdgcn_rcpf(1.f + __expf(-x));
}
__device__ __forceinline__ float fast_tanh(float x) {
  float e = __expf(2.f * x);
  return 1.f - 2.f * __builtin_amdgcn_rcpf(e + 1.f);
}
__device__ __forceinline__ void load_frag_pair(const unsigned short* sb, int l15, int quad,
                                               bf16x8& f0, bf16x8& f1) {
  const unsigned long long* a = (const unsigned long long*)(sb + l15 * 64 + quad * 8);
  const unsigned long long* b = (const unsigned long long*)(sb + l15 * 64 + 32 + quad * 8);
  union { bf16x8 v; unsigned long long u[2]; } c0, c1;
  c0.u[0] = __hip_atomic_load(&a[0], __ATOMIC_RELAXED, AG);
  c0.u[1] = __hip_atomic_load(&a[1], __ATOMIC_RELAXED, AG);
  c1.u[0] = __hip_atomic_load(&b[0], __ATOMIC_RELAXED, AG);
  c1.u[1] = __hip_atomic_load(&b[1], __ATOMIC_RELAXED, AG);
  f0 = c0.v; f1 = c1.v;
}

// ---------------- Kernel A: 2+2 split with single ring boundary ----------------
__global__ __launch_bounds__(512, 2) void lstm_split(Params p)
{
  const int bid   = blockIdx.x;
  const int role  = bid >> 6;          // 0: L0+L1, 1: L2+L3
  const int chunk = bid & 63;
  const int b0    = chunk * 16;
  const int tid   = threadIdx.x;
  const int wave  = tid >> 6;          // 0..7
  const int grp   = wave >> 2;         // layer group within block
  const int w     = wave & 3;          // cols [16w,16w+16) of each gate
  const int lane  = tid & 63;
  const int quad  = lane >> 4;
  const int l15   = lane & 15;
  const int L     = role * 2 + grp;    // global layer

  __shared__ __bf16 tiles[2][2][1024]; // [parity][group][swizzled 16x64 h tile]
  __shared__ float  s_fc1w[2048];
  __shared__ float  s_z[512];
  __shared__ float  s_fc1b[32];
  __shared__ float  s_fc2w[96];
  __shared__ float  s_fc2b[3];

  int* flagp = (int*)p.ws + chunk * 16;                 // 64B stride per chunk
  int* ackp  = (int*)(p.ws + 16 * 1024) + chunk * 16;
  unsigned short* ringc = (unsigned short*)(p.ws + 32 * 1024) + (size_t)chunk * p.R * 1024;
  const int RM = p.Rmask;

  // ---- weight fragments wf[gate][chunk]: 0-1 = Wih(K0..63), 2-3 = Whh(K0..63) ----
  bf16x8 wf[4][4];
  float  bias[4];
  {
    const float* wih = p.wih[L];
    const float* whh = p.whh[L];
    const float* bih = p.bih[L];
    const float* bhh = p.bhh[L];
#pragma unroll
    for (int g = 0; g < 4; g++) {
      int n = g * 64 + w * 16 + l15;   // B-frag: lane&15 = n, k = 32*chunk + quad*8 + j
      bias[g] = bih[n] + bhh[n];
      if (L == 0) {                    // w_ih_0 is (256,4): K-pad to 32, chunk1 unused
        bf16x8 f = bfzero();
        if (quad == 0) {
#pragma unroll
          for (int j = 0; j < 4; j++) f[j] = (__bf16)wih[n * 4 + j];
        }
        wf[g][0] = f; wf[g][1] = bfzero();
      } else {
#pragma unroll
        for (int q = 0; q < 2; q++) {
          const float* s = wih + n * 64 + q * 32 + quad * 8;
          bf16x8 f;
#pragma unroll
          for (int j = 0; j < 8; j++) f[j] = (__bf16)s[j];
          wf[g][q] = f;
        }
      }
#pragma unroll
      for (int q = 0; q < 2; q++) {
        const float* s = whh + n * 64 + q * 32 + quad * 8;
        bf16x8 f;
#pragma unroll
        for (int j = 0; j < 8; j++) f[j] = (__bf16)s[j];
        wf[g][2 + q] = f;
      }
    }
  }

  { int* ti = (int*)tiles; for (int i = tid; i < 2048; i += 512) ti[i] = 0; }
  float cst[4] = {0.f, 0.f, 0.f, 0.f};

  // protocol state (lane-0 meaningful; broadcast by shfl)
  int W = 0, f_pend = 0;
  int ackW = -1000000000, a_pend = -1000000000;
  bf16x8 xA0 = bfzero(), xA1 = bfzero();

  if (role == 0) {
    if (grp == 0 && quad == 0) {
      const float4 xv = *(const float4*)(p.x + ((size_t)(b0 + l15) * TLEN) * 4);
      bf16x8 f = bfzero();
      f[0] = (__bf16)xv.x; f[1] = (__bf16)xv.y; f[2] = (__bf16)xv.z; f[3] = (__bf16)xv.w;
      xA0 = f;
    }
  } else if (grp == 0) {
    // start-gate: wait until producer is D supersteps ahead, then load slot 0
    const int G = (p.D > 2) ? p.D : 2;
    int v = 0, it = 0;
    do {
      if (lane == 0) v = __hip_atomic_load(flagp, __ATOMIC_ACQUIRE, AG);
      v = __shfl(v, 0);
      if (v >= G) break;
      __builtin_amdgcn_s_sleep(2);
    } while (++it < SPIN_CAP);
    W = v;
    load_frag_pair(ringc, l15, quad, xA0, xA1);
  }
  __syncthreads();

  for (int s = 0; s < TLEN + 1; s++) {
    const int t  = s - grp;
    const int pr = s & 1, pw = pr ^ 1;
    bf16x8 xN0 = xA0, xN1 = xA1;

    if ((unsigned)t < (unsigned)TLEN) {
      // input fragments
      bf16x8 if0, if1;
      if (grp == 0) { if0 = xA0; if1 = xA1; }
      else {
        const __bf16* src = tiles[pr][0];
        int sg0 = quad ^ (l15 & 7);
        int sg1 = (4 + quad) ^ (l15 & 7);
        if0 = *(const bf16x8*)&src[l15 * 64 + sg0 * 8];
        if1 = *(const bf16x8*)&src[l15 * 64 + sg1 * 8];
      }
      // own recurrent h fragments
      bf16x8 hf0, hf1;
      {
        const __bf16* src = tiles[pr][grp];
        int sg0 = quad ^ (l15 & 7);
        int sg1 = (4 + quad) ^ (l15 & 7);
        hf0 = *(const bf16x8*)&src[l15 * 64 + sg0 * 8];
        hf1 = *(const bf16x8*)&src[l15 * 64 + sg1 * 8];
      }

      f32x4 acc[4];
#pragma unroll
      for (int g = 0; g < 4; g++) { f32x4 a = {bias[g], bias[g], bias[g], bias[g]}; acc[g] = a; }
      if (L == 0) {
#pragma unroll
        for (int g = 0; g < 4; g++)
          acc[g] = __builtin_amdgcn_mfma_f32_16x16x32_bf16(if0, wf[g][0], acc[g], 0, 0, 0);
      } else {
#pragma unroll
        for (int g = 0; g < 4; g++) {
          acc[g] = __builtin_amdgcn_mfma_f32_16x16x32_bf16(if0, wf[g][0], acc[g], 0, 0, 0);
          acc[g] = __builtin_amdgcn_mfma_f32_16x16x32_bf16(if1, wf[g][1], acc[g], 0, 0, 0);
        }
      }
#pragma unroll
      for (int g = 0; g < 4; g++) {
        acc[g] = __builtin_amdgcn_mfma_f32_16x16x32_bf16(hf0, wf[g][2], acc[g], 0, 0, 0);
        acc[g] = __builtin_amdgcn_mfma_f32_16x16x32_bf16(hf1, wf[g][3], acc[g], 0, 0, 0);
      }

      // x prefetch (producer layer-0) while MFMAs are in flight
      if (role == 0 && grp == 0 && quad == 0 && t + 1 < TLEN) {
        const float4 xv = *(const float4*)(p.x + ((size_t)(b0 + l15) * TLEN + (t + 1)) * 4);
        bf16x8 f = bfzero();
        f[0] = (__bf16)xv.x; f[1] = (__bf16)xv.y; f[2] = (__bf16)xv.z; f[3] = (__bf16)xv.w;
        xN0 = f;
      }
      // producer ring-reuse guard: overwriting slot t&RM clobbers step t-R
      if (role == 0 && grp == 1 && t >= p.R && ackW < t + 1 - p.R) {
        int v = ackW, it = 0;
        do {
          if (lane == 0) v = __hip_atomic_load(ackp, __ATOMIC_ACQUIRE, AG);
          v = __shfl(v, 0);
          if (v >= t + 1 - p.R) break;
          __builtin_amdgcn_s_sleep(2);
        } while (++it < SPIN_CAP);
        ackW = v;
      }

      // per-lane cell: lane holds (row m = quad*4+r, col = w*16+l15)
      const int col = w * 16 + l15;
      __bf16* dst = tiles[pw][grp];
      unsigned hb[4];
#pragma unroll
      for (int r = 0; r < 4; r++) {
        float ig = fast_sigmoid(acc[0][r]);
        float fg = fast_sigmoid(acc[1][r]);
        float gg = fast_tanh(acc[2][r]);
        float og = fast_sigmoid(acc[3][r]);
        float c = fg * cst[r] + ig * gg;
        cst[r] = c;
        float h = og * fast_tanh(c);
        __bf16 hbf = (__bf16)h;
        union { __bf16 b; unsigned short s; } cv; cv.b = hbf;
        hb[r] = cv.s;
        int m  = quad * 4 + r;
        int sg = (col >> 3) ^ (m & 7);
        dst[m * 64 + sg * 8 + (col & 7)] = hbf;
      }
      // producer publishes h1(t) into ring slot t&RM (pre-barrier; barrier drains vmcnt)
      if (role == 0 && grp == 1) {
        unsigned* rdst = (unsigned*)(ringc + (size_t)(t & RM) * 1024);
#pragma unroll
        for (int r = 0; r < 4; r++) {
          unsigned v = hb[r];
          unsigned o = (unsigned)__shfl_xor((int)v, 1);
          if ((lane & 1) == 0) {
            int m = quad * 4 + r;
            __hip_atomic_store(&rdst[(m * 64 + col) >> 1], v | (o << 16), __ATOMIC_RELAXED, AG);
          }
        }
      }
    }

    __syncthreads();  // publishes LDS tiles; drains producer's ring stores

    if (role == 0) {
      if (tid == 0 && s >= 1)
        __hip_atomic_store(flagp, s, __ATOMIC_RELAXED, AG);   // h1 steps <= s-1 published
      if (grp == 1) {
        int am = __shfl(a_pend, 0);
        if (am > ackW) ackW = am;
        if (lane == 0) a_pend = __hip_atomic_load(ackp, __ATOMIC_RELAXED, AG);
      }
    } else {
      if (grp == 0) {
        int fm = __shfl(f_pend, 0);
        if (fm > W) W = fm;
        if (lane == 0) f_pend = __hip_atomic_load(flagp, __ATOMIC_ACQUIRE, AG);
        const int c = s;
        if (c + 1 < TLEN) {           // prefetch slot c+1 (needs flag >= c+2)
          if (W < c + 2) {
            int v = W, it = 0;
            do {
              if (lane == 0) v = __hip_atomic_load(flagp, __ATOMIC_ACQUIRE, AG);
              v = __shfl(v, 0);
              if (v >= c + 2) break;
              __builtin_amdgcn_s_sleep(2);
            } while (++it < SPIN_CAP);
            W = v;
          }
          load_frag_pair(ringc + (size_t)((c + 1) & RM) * 1024, l15, quad, xN0, xN1);
        }
      }
      if (tid == 0)
        __hip_atomic_store(ackp, s, __ATOMIC_RELAXED, AG);    // completed superstep s
    }
    xA0 = xN0; xA1 = xN1;
  }

  // ---- FC head + softmax (consumer blocks; L3 final h at superstep 512 -> parity 1) ----
  if (role == 1) {
    for (int i = tid; i < 2048; i += 512) s_fc1w[i] = p.fc1w[i];
    if (tid < 32) s_fc1b[tid] = p.fc1b[tid];
    if (tid < 96) s_fc2w[tid] = p.fc2w[tid];
    if (tid < 3)  s_fc2b[tid] = p.fc2b[tid];
    __syncthreads();
    {
      int m = tid >> 5, u = tid & 31;
      float sacc = s_fc1b[u];
      const float* wrow = &s_fc1w[u * 64];
      const __bf16* hfin = tiles[1][1];
#pragma unroll
      for (int k = 0; k < 64; k++) {
        int sg = (k >> 3) ^ (m & 7);
        sacc += (float)hfin[m * 64 + sg * 8 + (k & 7)] * wrow[k];
      }
      s_z[m * 32 + u] = fmaxf(sacc, 0.f);
    }
    __syncthreads();
    if (tid < 16) {
      int m = tid;
      float lg[3];
#pragma unroll
      for (int v = 0; v < 3; v++) {
        float sv = s_fc2b[v];
#pragma unroll
        for (int u = 0; u < 32; u++) sv += s_z[m * 32 + u] * s_fc2w[v * 32 + u];
        lg[v] = sv;
      }
      float mx = fmaxf(lg[0], fmaxf(lg[1], lg[2]));
      float e0 = __expf(lg[0] - mx), e1 = __expf(lg[1] - mx), e2 = __expf(lg[2] - mx);
      float inv = 1.f / (e0 + e1 + e2);
      float* o = p.out + (size_t)(b0 + m) * 3;
      o[0] = e0 * inv; o[1] = e1 * inv; o[2] = e2 * inv;
    }
  }
}

// ---------------- Kernel B: round-4 fallback (all 4 layers in one block) ----------------
__global__ __launch_bounds__(1024) void lstm_fused(Params p)
{
  const int chunk = blockIdx.x;
  const int b0   = chunk * 16;
  const int tid  = threadIdx.x;
  const int wave = tid >> 6;
  const int L    = wave >> 2;
  const int w    = wave & 3;
  const int lane = tid & 63;
  const int quad = lane >> 4;
  const int l15  = lane & 15;

  __shared__ __bf16 tiles[2][5][16 * 64];
  __shared__ float  s_fc1w[2048];
  __shared__ float  s_z[512];
  __shared__ float  s_fc1b[32];
  __shared__ float  s_fc2w[96];
  __shared__ float  s_fc2b[3];

  bf16x8 wf[4][4];
  float  bias[4];
  {
    const float* wih = p.wih[L];
    const float* whh = p.whh[L];
    const float* bih = p.bih[L];
    const float* bhh = p.bhh[L];
#pragma unroll
    for (int g = 0; g < 4; g++) {
      int n = g * 64 + w * 16 + l15;
      bias[g] = bih[n] + bhh[n];
      if (L == 0) {
        bf16x8 f = bfzero();
        if (quad == 0) {
#pragma unroll
          for (int j = 0; j < 4; j++) f[j] = (__bf16)wih[n * 4 + j];
        }
        wf[g][0] = f; wf[g][1] = bfzero();
      } else {
#pragma unroll
        for (int q = 0; q < 2; q++) {
          const float* s = wih + n * 64 + q * 32 + quad * 8;
          bf16x8 f;
#pragma unroll
          for (int j = 0; j < 8; j++) f[j] = (__bf16)s[j];
          wf[g][q] = f;
        }
      }
#pragma unroll
      for (int q = 0; q < 2; q++) {
        const float* s = whh + n * 64 + q * 32 + quad * 8;
        bf16x8 f;
#pragma unroll
        for (int j = 0; j < 8; j++) f[j] = (__bf16)s[j];
        wf[g][2 + q] = f;
      }
    }
  }

  { int* ti = (int*)tiles; for (int i = tid; i < 5120; i += 1024) ti[i] = 0; }
  float cst[4] = {0.f, 0.f, 0.f, 0.f};

  if (wave == 0 && quad == 0) {
    const float4 xv = *(const float4*)(p.x + ((size_t)(b0 + l15) * TLEN) * 4);
    __bf16 v[4] = {(__bf16)xv.x, (__bf16)xv.y, (__bf16)xv.z, (__bf16)xv.w};
    *(float2*)&tiles[0][0][l15 * 64 + (l15 & 7) * 8] = *(float2*)v;
  }
  __syncthreads();

  for (int s = 0; s < TLEN + 3; s++) {
    const int t  = s - L;
    const int pr = s & 1;
    const int pw = pr ^ 1;

    if ((unsigned)t < (unsigned)TLEN) {
      const __bf16* in  = tiles[pr][L];
      const __bf16* own = tiles[pr][L + 1];
      const int sg0 = quad ^ (l15 & 7);
      const int sg1 = (4 + quad) ^ (l15 & 7);
      bf16x8 xf0 = *(const bf16x8*)&in [l15 * 64 + sg0 * 8];
      bf16x8 xf1 = *(const bf16x8*)&in [l15 * 64 + sg1 * 8];
      bf16x8 hf0 = *(const bf16x8*)&own[l15 * 64 + sg0 * 8];
      bf16x8 hf1 = *(const bf16x8*)&own[l15 * 64 + sg1 * 8];

      f32x4 acc[4];
#pragma unroll
      for (int g = 0; g < 4; g++) { f32x4 a = {bias[g], bias[g], bias[g], bias[g]}; acc[g] = a; }
#pragma unroll
      for (int g = 0; g < 4; g++) {
        acc[g] = __builtin_amdgcn_mfma_f32_16x16x32_bf16(xf0, wf[g][0], acc[g], 0, 0, 0);
        acc[g] = __builtin_amdgcn_mfma_f32_16x16x32_bf16(xf1, wf[g][1], acc[g], 0, 0, 0);
        acc[g] = __builtin_amdgcn_mfma_f32_16x16x32_bf16(hf0, wf[g][2], acc[g], 0, 0, 0);
        acc[g] = __builtin_amdgcn_mfma_f32_16x16x32_bf16(hf1, wf[g][3], acc[g], 0, 0, 0);
      }

      if (wave == 0 && quad == 0 && t + 1 < TLEN) {
        const float4 xv = *(const float4*)(p.x + ((size_t)(b0 + l15) * TLEN + (t + 1)) * 4);
        __bf16 v[4] = {(__bf16)xv.x, (__bf16)xv.y, (__bf16)xv.z, (__bf16)xv.w};
        *(float2*)&tiles[pw][0][l15 * 64 + (l15 & 7) * 8] = *(float2*)v;
      }

      const int col = w * 16 + l15;
      __bf16* dst = tiles[pw][L + 1];
#pragma unroll
      for (int r = 0; r < 4; r++) {
        float ig = fast_sigmoid(acc[0][r]);
        float fg = fast_sigmoid(acc[1][r]);
        float gg = fast_tanh(acc[2][r]);
        float og = fast_sigmoid(acc[3][r]);
        float c = fg * cst[r] + ig * gg;
        cst[r] = c;
        float h = og * fast_tanh(c);
        int m  = quad * 4 + r;
        int sg = (col >> 3) ^ (m & 7);
        dst[m * 64 + sg * 8 + (col & 7)] = (__bf16)h;
      }
    }
    __syncthreads();
  }

  for (int i = tid; i < 2048; i += 1024) s_fc1w[i] = p.fc1w[i];
  if (tid < 32) s_fc1b[tid] = p.fc1b[tid];
  if (tid < 96) s_fc2w[tid] = p.fc2w[tid];
  if (tid < 3)  s_fc2b[tid] = p.fc2b[tid];
  __syncthreads();
  if (tid < 512) {
    int m = tid >> 5, u = tid & 31;
    float sacc = s_fc1b[u];
    const float* wrow = &s_fc1w[u * 64];
    const __bf16* hfin = tiles[1][4];
#pragma unroll
    for (int k = 0; k < 64; k++) {
      int sg = (k >> 3) ^ (m & 7);
      sacc += (float)hfin[m * 64 + sg * 8 + (k & 7)] * wrow[k];
    }
    s_z[m * 32 + u] = fmaxf(sacc, 0.f);
  }
  __syncthreads();
  if (tid < 16) {
    int m = tid;
    float lg[3];
#pragma unroll
    for (int v = 0; v < 3; v++) {
      float sv = s_fc2b[v];
#pragma unroll
      for (int u = 0; u < 32; u++) sv += s_z[m * 32 + u] * s_fc2w[v * 32 + u];
      lg[v] = sv;
    }
    float mx = fmaxf(lg[0], fmaxf(lg[1], lg[2]));
    float e0 = __expf(lg[0] - mx), e1 = __expf(lg[1] - mx), e2 = __expf(lg[2] - mx);
    float inv = 1.f / (e0 + e1 + e2);
    float* o = p.out + (size_t)(b0 + m) * 3;
    o[0] = e0 * inv; o[1] = e1 * inv; o[2] = e2 * inv;
  }
}

extern "C" void kernel_launch(void* const* d_in, const int* in_sizes, int n_in,
                              void* d_out, int out_size, void* d_ws, size_t ws_size,
                              hipStream_t stream)
{
  (void)in_sizes; (void)n_in; (void)out_size;
  Params p;
  p.x = (const float*)d_in[0];
  for (int l = 0; l < 4; l++) {
    p.wih[l] = (const float*)d_in[1 + 4 * l];
    p.whh[l] = (const float*)d_in[2 + 4 * l];
    p.bih[l] = (const float*)d_in[3 + 4 * l];
    p.bhh[l] = (const float*)d_in[4 + 4 * l];
  }
  p.fc1w = (const float*)d_in[17];
  p.fc1b = (const float*)d_in[18];
  p.fc2w = (const float*)d_in[19];
  p.fc2b = (const float*)d_in[20];
  p.out = (float*)d_out;
  p.ws  = (char*)d_ws;

  // ring: 64 chunks x R slots x 2KB = R * 128KB, after 32KB of flags
  const size_t slotbytes = (size_t)NCH * 2048;
  const size_t avail = (ws_size > 32768) ? (ws_size - 32768) : 0;
  int R = 1;
  while (R < 32 && (size_t)(R * 2) * slotbytes <= avail) R <<= 1;

  if (R >= 8) {
    p.R = R; p.Rmask = R - 1;
    p.D = (R - 2 < 6) ? (R - 2) : 6;
    hipLaunchKernelGGL(lstm_split, dim3(128), dim3(512), 0, stream, p);
  } else {
    p.R = 0; p.Rmask = 0; p.D = 0;
    hipLaunchKernelGGL(lstm_fused, dim3(NCH), dim3(1024), 0, stream, p);
  }
}

// Round 6
// 1019.792 us; speedup vs baseline: 2.1789x; 2.1789x over previous
//
#include <hip/hip_runtime.h>

// 4-layer LSTM (B=1024,T=512,H=64,G=256) + FC head.
// Kernel A (lstm_split): 128 blocks x 512 threads. Block = (role, 16-row chunk):
//   role 0 = layers 0+1 (producer), role 1 = layers 2+3 + FC head (consumer).
//   Intra-block: wave-group (4 waves) = layer, skew 1 superstep, LDS tile handoff.
//   Cross-block boundary (h1 -> L2): ring in d_ws, CAP slots (>=16).
//   ROUND-6 FIX (vs round-5's 2.2ms): ALL ring stores / frag loads / flag+ack polls are
//   issued POST-barrier and consumed >=1 superstep later, so no __syncthreads ever drains
//   fresh cross-XCD traffic (round-5's producer paid ~900cyc/step in-barrier, starving the
//   consumer into a ~1.5us blocking poll every step). Consumer holds a 2-step register FIFO;
//   producer's flag trails its stores by one barrier (visibility-safe); ack is granted 2
//   steps early (load-retired, not consumed). Steady state: zero blocking polls.
// Kernel B (lstm_fused): round-4 fallback (852us) if ws too small for CAP>=16.

#define TLEN 512
#define NCH  64
#define AG   __HIP_MEMORY_SCOPE_AGENT
#define SPIN_CAP 2000000

typedef __bf16 bf16x8 __attribute__((ext_vector_type(8)));
typedef float  f32x4  __attribute__((ext_vector_type(4)));

struct Params {
  const float* x;
  const float* wih[4]; const float* whh[4];
  const float* bih[4]; const float* bhh[4];
  const float* fc1w; const float* fc1b;
  const float* fc2w; const float* fc2b;
  float* out; char* ws;
  int CAP; int CM;
};

__device__ __forceinline__ bf16x8 bfzero() {
  union { unsigned long long u[2]; bf16x8 v; } z; z.u[0] = 0ull; z.u[1] = 0ull; return z.v;
}
__device__ __forceinline__ float fast_sigmoid(float x) {
  return __builtin_amdgcn_rcpf(1.f + __expf(-x));
}
__device__ __forceinline__ float fast_tanh(float x) {
  float e = __expf(2.f * x);
  return 1.f - 2.f * __builtin_amdgcn_rcpf(e + 1.f);
}
__device__ __forceinline__ void load_frag_pair(const unsigned short* sb, int l15, int quad,
                                               bf16x8& f0, bf16x8& f1) {
  const unsigned long long* a = (const unsigned long long*)(sb + l15 * 64 + quad * 8);
  const unsigned long long* b = (const unsigned long long*)(sb + l15 * 64 + 32 + quad * 8);
  union { bf16x8 v; unsigned long long u[2]; } c0, c1;
  c0.u[0] = __hip_atomic_load(&a[0], __ATOMIC_RELAXED, AG);
  c0.u[1] = __hip_atomic_load(&a[1], __ATOMIC_RELAXED, AG);
  c1.u[0] = __hip_atomic_load(&b[0], __ATOMIC_RELAXED, AG);
  c1.u[1] = __hip_atomic_load(&b[1], __ATOMIC_RELAXED, AG);
  f0 = c0.v; f1 = c1.v;
}

// ---------------- Kernel A: 2+2 split, post-barrier pipelined ring ----------------
__global__ __launch_bounds__(512, 2) void lstm_split(Params p)
{
  const int bid   = blockIdx.x;
  const int role  = bid >> 6;          // 0: L0+L1 producer, 1: L2+L3 consumer (same bid%8 pair)
  const int chunk = bid & 63;
  const int b0    = chunk * 16;
  const int tid   = threadIdx.x;
  const int wave  = tid >> 6;
  const int grp   = wave >> 2;
  const int w     = wave & 3;
  const int lane  = tid & 63;
  const int quad  = lane >> 4;
  const int l15   = lane & 15;
  const int L     = role * 2 + grp;

  __shared__ __bf16 tiles[2][2][1024];
  __shared__ float  s_fc1w[2048];
  __shared__ float  s_z[512];
  __shared__ float  s_fc1b[32];
  __shared__ float  s_fc2w[96];
  __shared__ float  s_fc2b[3];

  int* flagp = (int*)p.ws + chunk * 16;
  int* ackp  = (int*)(p.ws + 16 * 1024) + chunk * 16;
  unsigned short* ringc = (unsigned short*)(p.ws + 32 * 1024) + (size_t)chunk * p.CAP * 1024;
  const int CAP = p.CAP, CM = p.CM;

  // ---- weight fragments wf[gate][chunk]: 0-1 = Wih(K0..63), 2-3 = Whh(K0..63) ----
  bf16x8 wf[4][4];
  float  bias[4];
  {
    const float* wih = p.wih[L];
    const float* whh = p.whh[L];
    const float* bih = p.bih[L];
    const float* bhh = p.bhh[L];
#pragma unroll
    for (int g = 0; g < 4; g++) {
      int n = g * 64 + w * 16 + l15;
      bias[g] = bih[n] + bhh[n];
      if (L == 0) {
        bf16x8 f = bfzero();
        if (quad == 0) {
#pragma unroll
          for (int j = 0; j < 4; j++) f[j] = (__bf16)wih[n * 4 + j];
        }
        wf[g][0] = f; wf[g][1] = bfzero();
      } else {
#pragma unroll
        for (int q = 0; q < 2; q++) {
          const float* s = wih + n * 64 + q * 32 + quad * 8;
          bf16x8 f;
#pragma unroll
          for (int j = 0; j < 8; j++) f[j] = (__bf16)s[j];
          wf[g][q] = f;
        }
      }
#pragma unroll
      for (int q = 0; q < 2; q++) {
        const float* s = whh + n * 64 + q * 32 + quad * 8;
        bf16x8 f;
#pragma unroll
        for (int j = 0; j < 8; j++) f[j] = (__bf16)s[j];
        wf[g][2 + q] = f;
      }
    }
  }

  { int* ti = (int*)tiles; for (int i = tid; i < 2048; i += 512) ti[i] = 0; }
  float cst[4] = {0.f, 0.f, 0.f, 0.f};

  int W = -1000000000, f_pend = -1000000000;     // consumer: producer flag watermark
  int ackW = -1000000000, a_pend = -1000000000;  // producer: consumer ack watermark
  bf16x8 xA0 = bfzero(), xA1 = bfzero();         // consumer FIFO: tile t
  bf16x8 xB0 = bfzero(), xB1 = bfzero();         // tile t+1

  if (role == 0) {
    if (grp == 0 && quad == 0) {
      const float4 xv = *(const float4*)(p.x + ((size_t)(b0 + l15) * TLEN) * 4);
      bf16x8 f = bfzero();
      f[0] = (__bf16)xv.x; f[1] = (__bf16)xv.y; f[2] = (__bf16)xv.z; f[3] = (__bf16)xv.w;
      xA0 = f;
    }
  } else if (grp == 0) {
    // start gate: tiles 0,1,2 ready (flag counts drained tiles)
    int v = -1000000000, it = 0;
    do {
      if (lane == 0) v = __hip_atomic_load(flagp, __ATOMIC_ACQUIRE, AG);
      v = __shfl(v, 0);
      if (v >= 3) break;
      __builtin_amdgcn_s_sleep(1);
    } while (++it < SPIN_CAP);
    W = v;
    load_frag_pair(ringc, l15, quad, xA0, xA1);
    load_frag_pair(ringc + 1024, l15, quad, xB0, xB1);
  }
  __syncthreads();

  const int SMAX = (role == 0) ? (TLEN + 2) : (TLEN + 1);
  for (int s = 0; s < SMAX; s++) {
    const int t  = s - grp;
    const int pr = s & 1, pw = pr ^ 1;
    unsigned hb[4];

    if ((unsigned)t < (unsigned)TLEN) {
      bf16x8 if0, if1;
      if (grp == 0) { if0 = xA0; if1 = xA1; }
      else {
        const __bf16* src = tiles[pr][0];
        int sg0 = quad ^ (l15 & 7);
        int sg1 = (4 + quad) ^ (l15 & 7);
        if0 = *(const bf16x8*)&src[l15 * 64 + sg0 * 8];
        if1 = *(const bf16x8*)&src[l15 * 64 + sg1 * 8];
      }
      bf16x8 hf0, hf1;
      {
        const __bf16* src = tiles[pr][grp];
        int sg0 = quad ^ (l15 & 7);
        int sg1 = (4 + quad) ^ (l15 & 7);
        hf0 = *(const bf16x8*)&src[l15 * 64 + sg0 * 8];
        hf1 = *(const bf16x8*)&src[l15 * 64 + sg1 * 8];
      }

      f32x4 acc[4];
#pragma unroll
      for (int g = 0; g < 4; g++) { f32x4 a = {bias[g], bias[g], bias[g], bias[g]}; acc[g] = a; }
      if (L == 0) {
#pragma unroll
        for (int g = 0; g < 4; g++)
          acc[g] = __builtin_amdgcn_mfma_f32_16x16x32_bf16(if0, wf[g][0], acc[g], 0, 0, 0);
      } else {
#pragma unroll
        for (int g = 0; g < 4; g++) {
          acc[g] = __builtin_amdgcn_mfma_f32_16x16x32_bf16(if0, wf[g][0], acc[g], 0, 0, 0);
          acc[g] = __builtin_amdgcn_mfma_f32_16x16x32_bf16(if1, wf[g][1], acc[g], 0, 0, 0);
        }
      }
#pragma unroll
      for (int g = 0; g < 4; g++) {
        acc[g] = __builtin_amdgcn_mfma_f32_16x16x32_bf16(hf0, wf[g][2], acc[g], 0, 0, 0);
        acc[g] = __builtin_amdgcn_mfma_f32_16x16x32_bf16(hf1, wf[g][3], acc[g], 0, 0, 0);
      }

      if (role == 0 && grp == 0 && quad == 0 && t + 1 < TLEN) {
        const float4 xv = *(const float4*)(p.x + ((size_t)(b0 + l15) * TLEN + (t + 1)) * 4);
        bf16x8 f = bfzero();
        f[0] = (__bf16)xv.x; f[1] = (__bf16)xv.y; f[2] = (__bf16)xv.z; f[3] = (__bf16)xv.w;
        xA0 = f;                      // producer L0 uses xA as its x register
      }

      const int col = w * 16 + l15;
      __bf16* dst = tiles[pw][grp];
#pragma unroll
      for (int r = 0; r < 4; r++) {
        float ig = fast_sigmoid(acc[0][r]);
        float fg = fast_sigmoid(acc[1][r]);
        float gg = fast_tanh(acc[2][r]);
        float og = fast_sigmoid(acc[3][r]);
        float c = fg * cst[r] + ig * gg;
        cst[r] = c;
        float h = og * fast_tanh(c);
        __bf16 hbf = (__bf16)h;
        union { __bf16 b; unsigned short s; } cv; cv.b = hbf;
        hb[r] = cv.s;
        int m  = quad * 4 + r;
        int sg = (col >> 3) ^ (m & 7);
        dst[m * 64 + sg * 8 + (col & 7)] = hbf;
      }
    }

    __syncthreads();  // drains only step-old global traffic + this step's LDS

    // -------- post-barrier cross-block work (fire & forget) --------
    if (role == 0) {
      if (grp == 1 && (unsigned)t < (unsigned)TLEN) {
        // ack watermark: overlapped relaxed poll, materialized next step
        int am = __shfl(a_pend, 0);
        if (am > ackW) ackW = am;
        if (lane == 0) a_pend = __hip_atomic_load(ackp, __ATOMIC_RELAXED, AG);
        // reuse guard: storing slot t&CM overwrites step t-CAP; need ack >= t-CAP+1
        if (t >= CAP && ackW < t - CAP + 1) {
          int v = ackW, it = 0;
          do {
            if (lane == 0) v = __hip_atomic_load(ackp, __ATOMIC_ACQUIRE, AG);
            v = __shfl(v, 0);
            if (v >= t - CAP + 1) break;
            __builtin_amdgcn_s_sleep(1);
          } while (++it < SPIN_CAP);
          ackW = v;
        }
        const int col = w * 16 + l15;
        unsigned* rdst = (unsigned*)(ringc + (size_t)(t & CM) * 1024);
#pragma unroll
        for (int r = 0; r < 4; r++) {
          unsigned v = hb[r];
          unsigned o = (unsigned)__shfl_xor((int)v, 1);
          if ((lane & 1) == 0) {
            int m = quad * 4 + r;
            __hip_atomic_store(&rdst[(m * 64 + col) >> 1], v | (o << 16), __ATOMIC_RELAXED, AG);
          }
        }
      }
      // flag: stores issued post-barrier(k) are drained by barrier(k+1);
      // at post-barrier(s), tiles <= s-2 are globally visible -> flag = s-1 tiles.
      if (tid == 0 && s >= 2)
        __hip_atomic_store(flagp, s - 1, __ATOMIC_RELAXED, AG);
    } else {
      if (grp == 0) {
        int fm = __shfl(f_pend, 0);
        if (fm > W) W = fm;
        if (lane == 0) f_pend = __hip_atomic_load(flagp, __ATOMIC_RELAXED, AG);
        if (t + 2 < TLEN) {           // prefetch tile t+2 (needs flag >= t+3)
          if (W < t + 3) {
            int v = W, it = 0;
            do {
              if (lane == 0) v = __hip_atomic_load(flagp, __ATOMIC_ACQUIRE, AG);
              v = __shfl(v, 0);
              if (v >= t + 3) break;
              __builtin_amdgcn_s_sleep(1);
            } while (++it < SPIN_CAP);
            W = v;
          }
          bf16x8 xN0, xN1;
          load_frag_pair(ringc + (size_t)((t + 2) & CM) * 1024, l15, quad, xN0, xN1);
          xA0 = xB0; xA1 = xB1; xB0 = xN0; xB1 = xN1;
        } else {
          xA0 = xB0; xA1 = xB1;
        }
      }
      // ack: slot s+1's load was issued post-barrier(s-1) and retired by barrier(s)
      if (tid == 0)
        __hip_atomic_store(ackp, s + 2, __ATOMIC_RELAXED, AG);
    }
  }

  // ---- FC head + softmax (consumer; L3 final h at superstep 512 -> parity 1) ----
  if (role == 1) {
    for (int i = tid; i < 2048; i += 512) s_fc1w[i] = p.fc1w[i];
    if (tid < 32) s_fc1b[tid] = p.fc1b[tid];
    if (tid < 96) s_fc2w[tid] = p.fc2w[tid];
    if (tid < 3)  s_fc2b[tid] = p.fc2b[tid];
    __syncthreads();
    {
      int m = tid >> 5, u = tid & 31;
      float sacc = s_fc1b[u];
      const float* wrow = &s_fc1w[u * 64];
      const __bf16* hfin = tiles[1][1];
#pragma unroll
      for (int k = 0; k < 64; k++) {
        int sg = (k >> 3) ^ (m & 7);
        sacc += (float)hfin[m * 64 + sg * 8 + (k & 7)] * wrow[k];
      }
      s_z[m * 32 + u] = fmaxf(sacc, 0.f);
    }
    __syncthreads();
    if (tid < 16) {
      int m = tid;
      float lg[3];
#pragma unroll
      for (int v = 0; v < 3; v++) {
        float sv = s_fc2b[v];
#pragma unroll
        for (int u = 0; u < 32; u++) sv += s_z[m * 32 + u] * s_fc2w[v * 32 + u];
        lg[v] = sv;
      }
      float mx = fmaxf(lg[0], fmaxf(lg[1], lg[2]));
      float e0 = __expf(lg[0] - mx), e1 = __expf(lg[1] - mx), e2 = __expf(lg[2] - mx);
      float inv = 1.f / (e0 + e1 + e2);
      float* o = p.out + (size_t)(b0 + m) * 3;
      o[0] = e0 * inv; o[1] = e1 * inv; o[2] = e2 * inv;
    }
  }
}

// ---------------- Kernel B: round-4 fallback ----------------
__global__ __launch_bounds__(1024) void lstm_fused(Params p)
{
  const int chunk = blockIdx.x;
  const int b0   = chunk * 16;
  const int tid  = threadIdx.x;
  const int wave = tid >> 6;
  const int L    = wave >> 2;
  const int w    = wave & 3;
  const int lane = tid & 63;
  const int quad = lane >> 4;
  const int l15  = lane & 15;

  __shared__ __bf16 tiles[2][5][16 * 64];
  __shared__ float  s_fc1w[2048];
  __shared__ float  s_z[512];
  __shared__ float  s_fc1b[32];
  __shared__ float  s_fc2w[96];
  __shared__ float  s_fc2b[3];

  bf16x8 wf[4][4];
  float  bias[4];
  {
    const float* wih = p.wih[L];
    const float* whh = p.whh[L];
    const float* bih = p.bih[L];
    const float* bhh = p.bhh[L];
#pragma unroll
    for (int g = 0; g < 4; g++) {
      int n = g * 64 + w * 16 + l15;
      bias[g] = bih[n] + bhh[n];
      if (L == 0) {
        bf16x8 f = bfzero();
        if (quad == 0) {
#pragma unroll
          for (int j = 0; j < 4; j++) f[j] = (__bf16)wih[n * 4 + j];
        }
        wf[g][0] = f; wf[g][1] = bfzero();
      } else {
#pragma unroll
        for (int q = 0; q < 2; q++) {
          const float* s = wih + n * 64 + q * 32 + quad * 8;
          bf16x8 f;
#pragma unroll
          for (int j = 0; j < 8; j++) f[j] = (__bf16)s[j];
          wf[g][q] = f;
        }
      }
#pragma unroll
      for (int q = 0; q < 2; q++) {
        const float* s = whh + n * 64 + q * 32 + quad * 8;
        bf16x8 f;
#pragma unroll
        for (int j = 0; j < 8; j++) f[j] = (__bf16)s[j];
        wf[g][2 + q] = f;
      }
    }
  }

  { int* ti = (int*)tiles; for (int i = tid; i < 5120; i += 1024) ti[i] = 0; }
  float cst[4] = {0.f, 0.f, 0.f, 0.f};

  if (wave == 0 && quad == 0) {
    const float4 xv = *(const float4*)(p.x + ((size_t)(b0 + l15) * TLEN) * 4);
    __bf16 v[4] = {(__bf16)xv.x, (__bf16)xv.y, (__bf16)xv.z, (__bf16)xv.w};
    *(float2*)&tiles[0][0][l15 * 64 + (l15 & 7) * 8] = *(float2*)v;
  }
  __syncthreads();

  for (int s = 0; s < TLEN + 3; s++) {
    const int t  = s - L;
    const int pr = s & 1;
    const int pw = pr ^ 1;

    if ((unsigned)t < (unsigned)TLEN) {
      const __bf16* in  = tiles[pr][L];
      const __bf16* own = tiles[pr][L + 1];
      const int sg0 = quad ^ (l15 & 7);
      const int sg1 = (4 + quad) ^ (l15 & 7);
      bf16x8 xf0 = *(const bf16x8*)&in [l15 * 64 + sg0 * 8];
      bf16x8 xf1 = *(const bf16x8*)&in [l15 * 64 + sg1 * 8];
      bf16x8 hf0 = *(const bf16x8*)&own[l15 * 64 + sg0 * 8];
      bf16x8 hf1 = *(const bf16x8*)&own[l15 * 64 + sg1 * 8];

      f32x4 acc[4];
#pragma unroll
      for (int g = 0; g < 4; g++) { f32x4 a = {bias[g], bias[g], bias[g], bias[g]}; acc[g] = a; }
#pragma unroll
      for (int g = 0; g < 4; g++) {
        acc[g] = __builtin_amdgcn_mfma_f32_16x16x32_bf16(xf0, wf[g][0], acc[g], 0, 0, 0);
        acc[g] = __builtin_amdgcn_mfma_f32_16x16x32_bf16(xf1, wf[g][1], acc[g], 0, 0, 0);
        acc[g] = __builtin_amdgcn_mfma_f32_16x16x32_bf16(hf0, wf[g][2], acc[g], 0, 0, 0);
        acc[g] = __builtin_amdgcn_mfma_f32_16x16x32_bf16(hf1, wf[g][3], acc[g], 0, 0, 0);
      }

      if (wave == 0 && quad == 0 && t + 1 < TLEN) {
        const float4 xv = *(const float4*)(p.x + ((size_t)(b0 + l15) * TLEN + (t + 1)) * 4);
        __bf16 v[4] = {(__bf16)xv.x, (__bf16)xv.y, (__bf16)xv.z, (__bf16)xv.w};
        *(float2*)&tiles[pw][0][l15 * 64 + (l15 & 7) * 8] = *(float2*)v;
      }

      const int col = w * 16 + l15;
      __bf16* dst = tiles[pw][L + 1];
#pragma unroll
      for (int r = 0; r < 4; r++) {
        float ig = fast_sigmoid(acc[0][r]);
        float fg = fast_sigmoid(acc[1][r]);
        float gg = fast_tanh(acc[2][r]);
        float og = fast_sigmoid(acc[3][r]);
        float c = fg * cst[r] + ig * gg;
        cst[r] = c;
        float h = og * fast_tanh(c);
        int m  = quad * 4 + r;
        int sg = (col >> 3) ^ (m & 7);
        dst[m * 64 + sg * 8 + (col & 7)] = (__bf16)h;
      }
    }
    __syncthreads();
  }

  for (int i = tid; i < 2048; i += 1024) s_fc1w[i] = p.fc1w[i];
  if (tid < 32) s_fc1b[tid] = p.fc1b[tid];
  if (tid < 96) s_fc2w[tid] = p.fc2w[tid];
  if (tid < 3)  s_fc2b[tid] = p.fc2b[tid];
  __syncthreads();
  if (tid < 512) {
    int m = tid >> 5, u = tid & 31;
    float sacc = s_fc1b[u];
    const float* wrow = &s_fc1w[u * 64];
    const __bf16* hfin = tiles[1][4];
#pragma unroll
    for (int k = 0; k < 64; k++) {
      int sg = (k >> 3) ^ (m & 7);
      sacc += (float)hfin[m * 64 + sg * 8 + (k & 7)] * wrow[k];
    }
    s_z[m * 32 + u] = fmaxf(sacc, 0.f);
  }
  __syncthreads();
  if (tid < 16) {
    int m = tid;
    float lg[3];
#pragma unroll
    for (int v = 0; v < 3; v++) {
      float sv = s_fc2b[v];
#pragma unroll
      for (int u = 0; u < 32; u++) sv += s_z[m * 32 + u] * s_fc2w[v * 32 + u];
      lg[v] = sv;
    }
    float mx = fmaxf(lg[0], fmaxf(lg[1], lg[2]));
    float e0 = __expf(lg[0] - mx), e1 = __expf(lg[1] - mx), e2 = __expf(lg[2] - mx);
    float inv = 1.f / (e0 + e1 + e2);
    float* o = p.out + (size_t)(b0 + m) * 3;
    o[0] = e0 * inv; o[1] = e1 * inv; o[2] = e2 * inv;
  }
}

extern "C" void kernel_launch(void* const* d_in, const int* in_sizes, int n_in,
                              void* d_out, int out_size, void* d_ws, size_t ws_size,
                              hipStream_t stream)
{
  (void)in_sizes; (void)n_in; (void)out_size;
  Params p;
  p.x = (const float*)d_in[0];
  for (int l = 0; l < 4; l++) {
    p.wih[l] = (const float*)d_in[1 + 4 * l];
    p.whh[l] = (const float*)d_in[2 + 4 * l];
    p.bih[l] = (const float*)d_in[3 + 4 * l];
    p.bhh[l] = (const float*)d_in[4 + 4 * l];
  }
  p.fc1w = (const float*)d_in[17];
  p.fc1b = (const float*)d_in[18];
  p.fc2w = (const float*)d_in[19];
  p.fc2b = (const float*)d_in[20];
  p.out = (float*)d_out;
  p.ws  = (char*)d_ws;

  // ring: 64 chunks x CAP slots x 2KB = CAP * 128KB, after 32KB flags
  const size_t avail = (ws_size > 32768) ? (ws_size - 32768) : 0;
  int CAP = 1;
  while (CAP < 64 && (size_t)(CAP * 2) * (NCH * 2048ull) <= avail) CAP <<= 1;

  if (CAP >= 16) {
    p.CAP = CAP; p.CM = CAP - 1;
    hipLaunchKernelGGL(lstm_split, dim3(128), dim3(512), 0, stream, p);
  } else {
    p.CAP = 0; p.CM = 0;
    hipLaunchKernelGGL(lstm_fused, dim3(NCH), dim3(1024), 0, stream, p);
  }
}

// Round 7
// 881.438 us; speedup vs baseline: 2.5209x; 1.1570x over previous
//
#include <hip/hip_runtime.h>

// 4-layer LSTM (B=1024,T=512,H=64,G=256) + FC head.
// Kernel A (lstm_split): 128 blocks x 512 threads. Block = (role, 16-row chunk):
//   role 0 = layers 0+1 (producer), role 1 = layers 2+3 + FC head (consumer).
//   Intra-block: wave-group (4 waves) = layer, skew 1 superstep, LDS tile handoff.
//   Cross-block boundary (h1 -> L2): ring in d_ws, CAP slots (>=16 guaranteed: r5/r6 ran split).
// ROUND-7 FIXES (vs round-6's 1019us, ~2900cyc/step stall measured):
//   (a) start-gate skew 10 supersteps (round-6 had skew 4 = zero slack -> the "rare"
//       blocking flag poll fired EVERY step, ~900cyc+sleep each).
//   (b) depth-3 register FIFO with rotation one superstep AFTER load issue: post-barrier(s)
//       rotates xA<-xB<-xC (waits only on a load issued a full superstep ago = hidden), THEN
//       issues tile t+3 into xC. Round-6 rotated at issue -> vmcnt(0) exposed ~900cyc/step.
//       Producer's x fetch gets the same treatment (raw float4 post-barrier, convert next step).
// Protocol safety: ack=s+2 claims tiles<=s+1 retired (their loads drained by own barrier >=1
// step earlier); producer reuse-guard needs skew D <= CAP-1 (11 <= 15 ok, slack 6 both sides).
// Kernel B (lstm_fused): round-4 fallback (852us) if ws too small for CAP>=16.

#define TLEN 512
#define NCH  64
#define AG   __HIP_MEMORY_SCOPE_AGENT
#define SPIN_CAP 2000000
#define GATE 10

typedef __bf16 bf16x8 __attribute__((ext_vector_type(8)));
typedef float  f32x4  __attribute__((ext_vector_type(4)));

struct Params {
  const float* x;
  const float* wih[4]; const float* whh[4];
  const float* bih[4]; const float* bhh[4];
  const float* fc1w; const float* fc1b;
  const float* fc2w; const float* fc2b;
  float* out; char* ws;
  int CAP; int CM;
};

__device__ __forceinline__ bf16x8 bfzero() {
  union { unsigned long long u[2]; bf16x8 v; } z; z.u[0] = 0ull; z.u[1] = 0ull; return z.v;
}
__device__ __forceinline__ float fast_sigmoid(float x) {
  return __builtin_amdgcn_rcpf(1.f + __expf(-x));
}
__device__ __forceinline__ float fast_tanh(float x) {
  float e = __expf(2.f * x);
  return 1.f - 2.f * __builtin_amdgcn_rcpf(e + 1.f);
}
__device__ __forceinline__ void load_frag_pair(const unsigned short* sb, int l15, int quad,
                                               bf16x8& f0, bf16x8& f1) {
  const unsigned long long* a = (const unsigned long long*)(sb + l15 * 64 + quad * 8);
  const unsigned long long* b = (const unsigned long long*)(sb + l15 * 64 + 32 + quad * 8);
  union { bf16x8 v; unsigned long long u[2]; } c0, c1;
  c0.u[0] = __hip_atomic_load(&a[0], __ATOMIC_RELAXED, AG);
  c0.u[1] = __hip_atomic_load(&a[1], __ATOMIC_RELAXED, AG);
  c1.u[0] = __hip_atomic_load(&b[0], __ATOMIC_RELAXED, AG);
  c1.u[1] = __hip_atomic_load(&b[1], __ATOMIC_RELAXED, AG);
  f0 = c0.v; f1 = c1.v;
}

// ---------------- Kernel A: 2+2 split, deep-slack post-barrier ring ----------------
__global__ __launch_bounds__(512, 2) void lstm_split(Params p)
{
  const int bid   = blockIdx.x;
  const int role  = bid >> 6;
  const int chunk = bid & 63;
  const int b0    = chunk * 16;
  const int tid   = threadIdx.x;
  const int wave  = tid >> 6;
  const int grp   = wave >> 2;
  const int w     = wave & 3;
  const int lane  = tid & 63;
  const int quad  = lane >> 4;
  const int l15   = lane & 15;
  const int L     = role * 2 + grp;

  __shared__ __bf16 tiles[2][2][1024];
  __shared__ float  s_fc1w[2048];
  __shared__ float  s_z[512];
  __shared__ float  s_fc1b[32];
  __shared__ float  s_fc2w[96];
  __shared__ float  s_fc2b[3];

  int* flagp = (int*)p.ws + chunk * 16;
  int* ackp  = (int*)(p.ws + 16 * 1024) + chunk * 16;
  unsigned short* ringc = (unsigned short*)(p.ws + 32 * 1024) + (size_t)chunk * p.CAP * 1024;
  const int CAP = p.CAP, CM = p.CM;

  // ---- weight fragments wf[gate][chunk]: 0-1 = Wih(K0..63), 2-3 = Whh(K0..63) ----
  bf16x8 wf[4][4];
  float  bias[4];
  {
    const float* wih = p.wih[L];
    const float* whh = p.whh[L];
    const float* bih = p.bih[L];
    const float* bhh = p.bhh[L];
#pragma unroll
    for (int g = 0; g < 4; g++) {
      int n = g * 64 + w * 16 + l15;
      bias[g] = bih[n] + bhh[n];
      if (L == 0) {
        bf16x8 f = bfzero();
        if (quad == 0) {
#pragma unroll
          for (int j = 0; j < 4; j++) f[j] = (__bf16)wih[n * 4 + j];
        }
        wf[g][0] = f; wf[g][1] = bfzero();
      } else {
#pragma unroll
        for (int q = 0; q < 2; q++) {
          const float* s = wih + n * 64 + q * 32 + quad * 8;
          bf16x8 f;
#pragma unroll
          for (int j = 0; j < 8; j++) f[j] = (__bf16)s[j];
          wf[g][q] = f;
        }
      }
#pragma unroll
      for (int q = 0; q < 2; q++) {
        const float* s = whh + n * 64 + q * 32 + quad * 8;
        bf16x8 f;
#pragma unroll
        for (int j = 0; j < 8; j++) f[j] = (__bf16)s[j];
        wf[g][2 + q] = f;
      }
    }
  }

  { int* ti = (int*)tiles; for (int i = tid; i < 2048; i += 512) ti[i] = 0; }
  float cst[4] = {0.f, 0.f, 0.f, 0.f};

  int W = -1000000000, f_pend = -1000000000;
  int ackW = -1000000000, a_pend = -1000000000;
  // FIFO registers: consumer grp0: xA=tile t, xB=t+1, xC=t+2 (in flight).
  // producer grp0: xA=x(t) bf16, xB=x(t+1) bf16, xraw=x(t+2) float4 in flight.
  bf16x8 xA0 = bfzero(), xA1 = bfzero();
  bf16x8 xB0 = bfzero(), xB1 = bfzero();
  bf16x8 xC0 = bfzero(), xC1 = bfzero();
  float4 xraw = {0.f, 0.f, 0.f, 0.f};

  if (role == 0) {
    if (grp == 0 && quad == 0) {
      const float* xb = p.x + (size_t)(b0 + l15) * TLEN * 4;
      const float4 x0 = *(const float4*)(xb);
      const float4 x1 = *(const float4*)(xb + 4);
      xraw = *(const float4*)(xb + 8);
      bf16x8 f = bfzero();
      f[0] = (__bf16)x0.x; f[1] = (__bf16)x0.y; f[2] = (__bf16)x0.z; f[3] = (__bf16)x0.w;
      xA0 = f;
      bf16x8 g = bfzero();
      g[0] = (__bf16)x1.x; g[1] = (__bf16)x1.y; g[2] = (__bf16)x1.z; g[3] = (__bf16)x1.w;
      xB0 = g;
    }
  } else if (grp == 0) {
    // start gate: deep skew (GATE supersteps of producer headroom)
    int v = -1000000000, it = 0;
    do {
      if (lane == 0) v = __hip_atomic_load(flagp, __ATOMIC_ACQUIRE, AG);
      v = __shfl(v, 0);
      if (v >= GATE) break;
      __builtin_amdgcn_s_sleep(1);
    } while (++it < SPIN_CAP);
    W = v;
    load_frag_pair(ringc,        l15, quad, xA0, xA1);
    load_frag_pair(ringc + 1024, l15, quad, xB0, xB1);
    load_frag_pair(ringc + 2048, l15, quad, xC0, xC1);
  }
  __syncthreads();

  const int SMAX = (role == 0) ? (TLEN + 2) : (TLEN + 1);
  for (int s = 0; s < SMAX; s++) {
    const int t  = s - grp;
    const int pr = s & 1, pw = pr ^ 1;
    unsigned hb[4];

    if ((unsigned)t < (unsigned)TLEN) {
      bf16x8 if0, if1;
      if (grp == 0) { if0 = xA0; if1 = xA1; }
      else {
        const __bf16* src = tiles[pr][0];
        int sg0 = quad ^ (l15 & 7);
        int sg1 = (4 + quad) ^ (l15 & 7);
        if0 = *(const bf16x8*)&src[l15 * 64 + sg0 * 8];
        if1 = *(const bf16x8*)&src[l15 * 64 + sg1 * 8];
      }
      bf16x8 hf0, hf1;
      {
        const __bf16* src = tiles[pr][grp];
        int sg0 = quad ^ (l15 & 7);
        int sg1 = (4 + quad) ^ (l15 & 7);
        hf0 = *(const bf16x8*)&src[l15 * 64 + sg0 * 8];
        hf1 = *(const bf16x8*)&src[l15 * 64 + sg1 * 8];
      }

      f32x4 acc[4];
#pragma unroll
      for (int g = 0; g < 4; g++) { f32x4 a = {bias[g], bias[g], bias[g], bias[g]}; acc[g] = a; }
      if (L == 0) {
#pragma unroll
        for (int g = 0; g < 4; g++)
          acc[g] = __builtin_amdgcn_mfma_f32_16x16x32_bf16(if0, wf[g][0], acc[g], 0, 0, 0);
      } else {
#pragma unroll
        for (int g = 0; g < 4; g++) {
          acc[g] = __builtin_amdgcn_mfma_f32_16x16x32_bf16(if0, wf[g][0], acc[g], 0, 0, 0);
          acc[g] = __builtin_amdgcn_mfma_f32_16x16x32_bf16(if1, wf[g][1], acc[g], 0, 0, 0);
        }
      }
#pragma unroll
      for (int g = 0; g < 4; g++) {
        acc[g] = __builtin_amdgcn_mfma_f32_16x16x32_bf16(hf0, wf[g][2], acc[g], 0, 0, 0);
        acc[g] = __builtin_amdgcn_mfma_f32_16x16x32_bf16(hf1, wf[g][3], acc[g], 0, 0, 0);
      }

      const int col = w * 16 + l15;
      __bf16* dst = tiles[pw][grp];
#pragma unroll
      for (int r = 0; r < 4; r++) {
        float ig = fast_sigmoid(acc[0][r]);
        float fg = fast_sigmoid(acc[1][r]);
        float gg = fast_tanh(acc[2][r]);
        float og = fast_sigmoid(acc[3][r]);
        float c = fg * cst[r] + ig * gg;
        cst[r] = c;
        float h = og * fast_tanh(c);
        __bf16 hbf = (__bf16)h;
        union { __bf16 b; unsigned short s; } cv; cv.b = hbf;
        hb[r] = cv.s;
        int m  = quad * 4 + r;
        int sg = (col >> 3) ^ (m & 7);
        dst[m * 64 + sg * 8 + (col & 7)] = hbf;
      }
    }

    __syncthreads();  // drains only step-old global traffic + this step's LDS

    // -------- post-barrier cross-block work (fire & forget; consumed >=1 step later) -----
    if (role == 0) {
      if (grp == 0) {
        // producer x FIFO: rotate, convert (load issued 1 superstep ago = hidden), reload
        xA0 = xB0;
        if (quad == 0) {
          bf16x8 f = bfzero();
          f[0] = (__bf16)xraw.x; f[1] = (__bf16)xraw.y;
          f[2] = (__bf16)xraw.z; f[3] = (__bf16)xraw.w;
          xB0 = f;
          if (t + 3 < TLEN)
            xraw = *(const float4*)(p.x + ((size_t)(b0 + l15) * TLEN + (t + 3)) * 4);
        }
      }
      if (grp == 1 && (unsigned)t < (unsigned)TLEN) {
        int am = __shfl(a_pend, 0);
        if (am > ackW) ackW = am;
        if (lane == 0) a_pend = __hip_atomic_load(ackp, __ATOMIC_RELAXED, AG);
        if (t >= CAP && ackW < t - CAP + 1) {          // reuse guard (slack ~CAP-1-skew)
          int v = ackW, it = 0;
          do {
            if (lane == 0) v = __hip_atomic_load(ackp, __ATOMIC_ACQUIRE, AG);
            v = __shfl(v, 0);
            if (v >= t - CAP + 1) break;
            __builtin_amdgcn_s_sleep(1);
          } while (++it < SPIN_CAP);
          ackW = v;
        }
        const int col = w * 16 + l15;
        unsigned* rdst = (unsigned*)(ringc + (size_t)(t & CM) * 1024);
#pragma unroll
        for (int r = 0; r < 4; r++) {
          unsigned v = hb[r];
          unsigned o = (unsigned)__shfl_xor((int)v, 1);
          if ((lane & 1) == 0) {
            int m = quad * 4 + r;
            __hip_atomic_store(&rdst[(m * 64 + col) >> 1], v | (o << 16), __ATOMIC_RELAXED, AG);
          }
        }
      }
      if (tid == 0 && s >= 2)
        __hip_atomic_store(flagp, s - 1, __ATOMIC_RELAXED, AG);
    } else {
      if (grp == 0) {
        int fm = __shfl(f_pend, 0);
        if (fm > W) W = fm;
        if (lane == 0) f_pend = __hip_atomic_load(flagp, __ATOMIC_RELAXED, AG);
        // rotate FIFO FIRST: xC's load was issued at post-barrier(s-1) -> hidden by superstep s
        xA0 = xB0; xA1 = xB1; xB0 = xC0; xB1 = xC1;
        if (t + 3 < TLEN) {           // then issue tile t+3 -> xC (needs flag >= t+4)
          if (W < t + 4) {
            int v = W, it = 0;
            do {
              if (lane == 0) v = __hip_atomic_load(flagp, __ATOMIC_ACQUIRE, AG);
              v = __shfl(v, 0);
              if (v >= t + 4) break;
              __builtin_amdgcn_s_sleep(1);
            } while (++it < SPIN_CAP);
            W = v;
          }
          load_frag_pair(ringc + (size_t)((t + 3) & CM) * 1024, l15, quad, xC0, xC1);
        }
      }
      if (tid == 0)
        __hip_atomic_store(ackp, s + 2, __ATOMIC_RELAXED, AG);
    }
  }

  // ---- FC head + softmax (consumer; L3 final h at superstep 512 -> parity 1) ----
  if (role == 1) {
    for (int i = tid; i < 2048; i += 512) s_fc1w[i] = p.fc1w[i];
    if (tid < 32) s_fc1b[tid] = p.fc1b[tid];
    if (tid < 96) s_fc2w[tid] = p.fc2w[tid];
    if (tid < 3)  s_fc2b[tid] = p.fc2b[tid];
    __syncthreads();
    {
      int m = tid >> 5, u = tid & 31;
      float sacc = s_fc1b[u];
      const float* wrow = &s_fc1w[u * 64];
      const __bf16* hfin = tiles[1][1];
#pragma unroll
      for (int k = 0; k < 64; k++) {
        int sg = (k >> 3) ^ (m & 7);
        sacc += (float)hfin[m * 64 + sg * 8 + (k & 7)] * wrow[k];
      }
      s_z[m * 32 + u] = fmaxf(sacc, 0.f);
    }
    __syncthreads();
    if (tid < 16) {
      int m = tid;
      float lg[3];
#pragma unroll
      for (int v = 0; v < 3; v++) {
        float sv = s_fc2b[v];
#pragma unroll
        for (int u = 0; u < 32; u++) sv += s_z[m * 32 + u] * s_fc2w[v * 32 + u];
        lg[v] = sv;
      }
      float mx = fmaxf(lg[0], fmaxf(lg[1], lg[2]));
      float e0 = __expf(lg[0] - mx), e1 = __expf(lg[1] - mx), e2 = __expf(lg[2] - mx);
      float inv = 1.f / (e0 + e1 + e2);
      float* o = p.out + (size_t)(b0 + m) * 3;
      o[0] = e0 * inv; o[1] = e1 * inv; o[2] = e2 * inv;
    }
  }
}

// ---------------- Kernel B: round-4 fallback ----------------
__global__ __launch_bounds__(1024) void lstm_fused(Params p)
{
  const int chunk = blockIdx.x;
  const int b0   = chunk * 16;
  const int tid  = threadIdx.x;
  const int wave = tid >> 6;
  const int L    = wave >> 2;
  const int w    = wave & 3;
  const int lane = tid & 63;
  const int quad = lane >> 4;
  const int l15  = lane & 15;

  __shared__ __bf16 tiles[2][5][16 * 64];
  __shared__ float  s_fc1w[2048];
  __shared__ float  s_z[512];
  __shared__ float  s_fc1b[32];
  __shared__ float  s_fc2w[96];
  __shared__ float  s_fc2b[3];

  bf16x8 wf[4][4];
  float  bias[4];
  {
    const float* wih = p.wih[L];
    const float* whh = p.whh[L];
    const float* bih = p.bih[L];
    const float* bhh = p.bhh[L];
#pragma unroll
    for (int g = 0; g < 4; g++) {
      int n = g * 64 + w * 16 + l15;
      bias[g] = bih[n] + bhh[n];
      if (L == 0) {
        bf16x8 f = bfzero();
        if (quad == 0) {
#pragma unroll
          for (int j = 0; j < 4; j++) f[j] = (__bf16)wih[n * 4 + j];
        }
        wf[g][0] = f; wf[g][1] = bfzero();
      } else {
#pragma unroll
        for (int q = 0; q < 2; q++) {
          const float* s = wih + n * 64 + q * 32 + quad * 8;
          bf16x8 f;
#pragma unroll
          for (int j = 0; j < 8; j++) f[j] = (__bf16)s[j];
          wf[g][q] = f;
        }
      }
#pragma unroll
      for (int q = 0; q < 2; q++) {
        const float* s = whh + n * 64 + q * 32 + quad * 8;
        bf16x8 f;
#pragma unroll
        for (int j = 0; j < 8; j++) f[j] = (__bf16)s[j];
        wf[g][2 + q] = f;
      }
    }
  }

  { int* ti = (int*)tiles; for (int i = tid; i < 5120; i += 1024) ti[i] = 0; }
  float cst[4] = {0.f, 0.f, 0.f, 0.f};

  if (wave == 0 && quad == 0) {
    const float4 xv = *(const float4*)(p.x + ((size_t)(b0 + l15) * TLEN) * 4);
    __bf16 v[4] = {(__bf16)xv.x, (__bf16)xv.y, (__bf16)xv.z, (__bf16)xv.w};
    *(float2*)&tiles[0][0][l15 * 64 + (l15 & 7) * 8] = *(float2*)v;
  }
  __syncthreads();

  for (int s = 0; s < TLEN + 3; s++) {
    const int t  = s - L;
    const int pr = s & 1;
    const int pw = pr ^ 1;

    if ((unsigned)t < (unsigned)TLEN) {
      const __bf16* in  = tiles[pr][L];
      const __bf16* own = tiles[pr][L + 1];
      const int sg0 = quad ^ (l15 & 7);
      const int sg1 = (4 + quad) ^ (l15 & 7);
      bf16x8 xf0 = *(const bf16x8*)&in [l15 * 64 + sg0 * 8];
      bf16x8 xf1 = *(const bf16x8*)&in [l15 * 64 + sg1 * 8];
      bf16x8 hf0 = *(const bf16x8*)&own[l15 * 64 + sg0 * 8];
      bf16x8 hf1 = *(const bf16x8*)&own[l15 * 64 + sg1 * 8];

      f32x4 acc[4];
#pragma unroll
      for (int g = 0; g < 4; g++) { f32x4 a = {bias[g], bias[g], bias[g], bias[g]}; acc[g] = a; }
#pragma unroll
      for (int g = 0; g < 4; g++) {
        acc[g] = __builtin_amdgcn_mfma_f32_16x16x32_bf16(xf0, wf[g][0], acc[g], 0, 0, 0);
        acc[g] = __builtin_amdgcn_mfma_f32_16x16x32_bf16(xf1, wf[g][1], acc[g], 0, 0, 0);
        acc[g] = __builtin_amdgcn_mfma_f32_16x16x32_bf16(hf0, wf[g][2], acc[g], 0, 0, 0);
        acc[g] = __builtin_amdgcn_mfma_f32_16x16x32_bf16(hf1, wf[g][3], acc[g], 0, 0, 0);
      }

      if (wave == 0 && quad == 0 && t + 1 < TLEN) {
        const float4 xv = *(const float4*)(p.x + ((size_t)(b0 + l15) * TLEN + (t + 1)) * 4);
        __bf16 v[4] = {(__bf16)xv.x, (__bf16)xv.y, (__bf16)xv.z, (__bf16)xv.w};
        *(float2*)&tiles[pw][0][l15 * 64 + (l15 & 7) * 8] = *(float2*)v;
      }

      const int col = w * 16 + l15;
      __bf16* dst = tiles[pw][L + 1];
#pragma unroll
      for (int r = 0; r < 4; r++) {
        float ig = fast_sigmoid(acc[0][r]);
        float fg = fast_sigmoid(acc[1][r]);
        float gg = fast_tanh(acc[2][r]);
        float og = fast_sigmoid(acc[3][r]);
        float c = fg * cst[r] + ig * gg;
        cst[r] = c;
        float h = og * fast_tanh(c);
        int m  = quad * 4 + r;
        int sg = (col >> 3) ^ (m & 7);
        dst[m * 64 + sg * 8 + (col & 7)] = (__bf16)h;
      }
    }
    __syncthreads();
  }

  for (int i = tid; i < 2048; i += 1024) s_fc1w[i] = p.fc1w[i];
  if (tid < 32) s_fc1b[tid] = p.fc1b[tid];
  if (tid < 96) s_fc2w[tid] = p.fc2w[tid];
  if (tid < 3)  s_fc2b[tid] = p.fc2b[tid];
  __syncthreads();
  if (tid < 512) {
    int m = tid >> 5, u = tid & 31;
    float sacc = s_fc1b[u];
    const float* wrow = &s_fc1w[u * 64];
    const __bf16* hfin = tiles[1][4];
#pragma unroll
    for (int k = 0; k < 64; k++) {
      int sg = (k >> 3) ^ (m & 7);
      sacc += (float)hfin[m * 64 + sg * 8 + (k & 7)] * wrow[k];
    }
    s_z[m * 32 + u] = fmaxf(sacc, 0.f);
  }
  __syncthreads();
  if (tid < 16) {
    int m = tid;
    float lg[3];
#pragma unroll
    for (int v = 0; v < 3; v++) {
      float sv = s_fc2b[v];
#pragma unroll
      for (int u = 0; u < 32; u++) sv += s_z[m * 32 + u] * s_fc2w[v * 32 + u];
      lg[v] = sv;
    }
    float mx = fmaxf(lg[0], fmaxf(lg[1], lg[2]));
    float e0 = __expf(lg[0] - mx), e1 = __expf(lg[1] - mx), e2 = __expf(lg[2] - mx);
    float inv = 1.f / (e0 + e1 + e2);
    float* o = p.out + (size_t)(b0 + m) * 3;
    o[0] = e0 * inv; o[1] = e1 * inv; o[2] = e2 * inv;
  }
}

extern "C" void kernel_launch(void* const* d_in, const int* in_sizes, int n_in,
                              void* d_out, int out_size, void* d_ws, size_t ws_size,
                              hipStream_t stream)
{
  (void)in_sizes; (void)n_in; (void)out_size;
  Params p;
  p.x = (const float*)d_in[0];
  for (int l = 0; l < 4; l++) {
    p.wih[l] = (const float*)d_in[1 + 4 * l];
    p.whh[l] = (const float*)d_in[2 + 4 * l];
    p.bih[l] = (const float*)d_in[3 + 4 * l];
    p.bhh[l] = (const float*)d_in[4 + 4 * l];
  }
  p.fc1w = (const float*)d_in[17];
  p.fc1b = (const float*)d_in[18];
  p.fc2w = (const float*)d_in[19];
  p.fc2b = (const float*)d_in[20];
  p.out = (float*)d_out;
  p.ws  = (char*)d_ws;

  // ring: 64 chunks x CAP slots x 2KB = CAP * 128KB, after 32KB flags
  const size_t avail = (ws_size > 32768) ? (ws_size - 32768) : 0;
  int CAP = 1;
  while (CAP < 64 && (size_t)(CAP * 2) * (NCH * 2048ull) <= avail) CAP <<= 1;

  if (CAP >= 16) {
    p.CAP = CAP; p.CM = CAP - 1;
    hipLaunchKernelGGL(lstm_split, dim3(128), dim3(512), 0, stream, p);
  } else {
    p.CAP = 0; p.CM = 0;
    hipLaunchKernelGGL(lstm_fused, dim3(NCH), dim3(1024), 0, stream, p);
  }
}